// Round 12
// baseline (418.614 us; speedup 1.0000x reference)
//
#include <hip/hip_runtime.h>

// GCN: N=100000, E=1600000, widths 128 -> 16 -> 64 -> 128 -> 1
// Round 12: more block-range overlap + head ILP.
//   - gemm1 (unscaled) fused under hist_rank (atomics <-> dense VALU overlap);
//     A's dinv-scale moved to spare blocks of the fill dispatch.
//   - head_k: 8 nodes per wave (halves per-wave W3 preload traffic, 2x MLP).
// Pipeline: [hist ∥ gemm1'] -> scan(+dinv) -> [fill ∥ scaleA] -> gather16(r1)
//           -> g16gemm2(r2) -> gather64 -> head.

#define NN 100000
#define NE 1600000
#define NB ((NN + 255) / 256)   // 391 blocks for scans

__device__ __forceinline__ float rdl_f(float v, int l) {
    return __int_as_float(__builtin_amdgcn_readlane(__float_as_int(v), l));
}

// ---------------- fused: histogram+rank (blocks < histBlocks) + gemm1 ----------------
// gemm1: A' = x @ W1 (unscaled; dinv not ready yet). Independent of hist.
__global__ __launch_bounds__(256) void hist_gemm1_k(const int* __restrict__ dst,
                                                    int* __restrict__ ideg,
                                                    int* __restrict__ rank,
                                                    const float* __restrict__ x,
                                                    const float* __restrict__ W1,
                                                    float* __restrict__ A,
                                                    int e, int n, int histBlocks) {
    __shared__ float sW[128 * 16];
    __shared__ float sIn[16][132];           // +4 pad
    if ((int)blockIdx.x < histBlocks) {
        int i = blockIdx.x * 256 + threadIdx.x;
        if (i < e) rank[i] = atomicAdd(&ideg[dst[i]], 1);
        return;
    }
    const int bid = blockIdx.x - histBlocks;
    const int tid = threadIdx.x;
    for (int i = tid; i < 128 * 16; i += 256) sW[i] = W1[i];
    const int row0 = bid * 16;
    const float4* in4 = (const float4*)x;
    for (int i = tid; i < 16 * 32; i += 256) {
        int r = i >> 5, kv = i & 31;
        int g = row0 + r;
        float4 v = make_float4(0.f, 0.f, 0.f, 0.f);
        if (g < n) v = in4[(long)g * 32 + kv];
        ((float4*)&sIn[r][0])[kv] = v;
    }
    __syncthreads();
    const int r = tid >> 4, m = tid & 15;
    const int g = row0 + r;
    if (g < n) {
        float acc = 0.0f;
#pragma unroll
        for (int k = 0; k < 128; ++k) acc += sIn[r][k] * sW[k * 16 + m];
        A[(long)g * 16 + m] = acc;           // unscaled
    }
}

// ---------------- scan pass 1 (+ fused dinv) ----------------
__global__ void scan_reduce_k(const int* __restrict__ ideg, int* __restrict__ bsum,
                              float* __restrict__ dinv, int n) {
    __shared__ int s[256];
    int i = blockIdx.x * 256 + threadIdx.x;
    int v = (i < n) ? ideg[i] : 0;
    if (i < n) dinv[i] = rsqrtf((float)v + 1.0f);  // +1 self loop
    s[threadIdx.x] = v;
    __syncthreads();
    for (int off = 128; off > 0; off >>= 1) {
        if (threadIdx.x < off) s[threadIdx.x] += s[threadIdx.x + off];
        __syncthreads();
    }
    if (threadIdx.x == 0) bsum[blockIdx.x] = s[0];
}

__global__ __launch_bounds__(512) void scan_partials_k(const int* __restrict__ bsum,
                                                       int* __restrict__ bofs, int nb) {
    __shared__ int s[512];
    int t = threadIdx.x;
    int v = (t < nb) ? bsum[t] : 0;
    s[t] = v;
    __syncthreads();
    for (int off = 1; off < 512; off <<= 1) {
        int a = (t >= off) ? s[t - off] : 0;
        __syncthreads();
        s[t] += a;
        __syncthreads();
    }
    if (t < nb) bofs[t] = s[t] - v;  // exclusive
}

__global__ void scan_final_k(const int* __restrict__ ideg, const int* __restrict__ bofs,
                             int* __restrict__ rowptr, int n, int e) {
    __shared__ int s[256];
    int i = blockIdx.x * 256 + threadIdx.x;
    int t = threadIdx.x;
    int v = (i < n) ? ideg[i] : 0;
    s[t] = v;
    __syncthreads();
    for (int off = 1; off < 256; off <<= 1) {
        int a = (t >= off) ? s[t - off] : 0;
        __syncthreads();
        s[t] += a;
        __syncthreads();
    }
    int excl = s[t] - v + bofs[blockIdx.x];
    if (i < n) rowptr[i] = excl;
    if (i == 0) rowptr[n] = e;
}

// ---------------- fused: CSR fill (blocks < fillBlocks) + A scale ----------------
// scale: A *= dinv[row] (in place, float4 over N*4 vecs). Needs dinv (ready).
__global__ __launch_bounds__(256) void fill_scale_k(const int* __restrict__ src,
                                                    const int* __restrict__ dst,
                                                    const int* __restrict__ rank,
                                                    const int* __restrict__ rowptr,
                                                    int* __restrict__ csr_src,
                                                    float* __restrict__ A,
                                                    const float* __restrict__ dinv,
                                                    int e, int n, int fillBlocks) {
    if ((int)blockIdx.x < fillBlocks) {
        int i = blockIdx.x * 256 + threadIdx.x;
        if (i < e) csr_src[rowptr[dst[i]] + rank[i]] = src[i];
        return;
    }
    const int bid = blockIdx.x - fillBlocks;
    int vec = bid * 256 + threadIdx.x;       // float4 index over A (n*4 vecs)
    if (vec < n * 4) {
        float4* A4 = (float4*)A;
        float d = dinv[vec >> 2];
        float4 v = A4[vec];
        A4[vec] = make_float4(v.x * d, v.y * d, v.z * d, v.w * d);
    }
}

// ---------------- pull-gather, 16 ch (weight-free) ----------------
template<bool BIAS_RELU, bool OUT_SCALE>
__global__ __launch_bounds__(256) void gather16_k(const int* __restrict__ rowptr,
                                                  const int* __restrict__ csr_src,
                                                  const float* __restrict__ dinv,
                                                  const float* __restrict__ hs,
                                                  const float* __restrict__ bias,
                                                  float* __restrict__ outp, int n) {
    const int g = (blockIdx.x * 256 + threadIdx.x) >> 6;
    if (g >= n) return;
    const int lane = threadIdx.x & 63;
    const int q = lane & 3;                 // float4 index within 16-ch row
    const int sub = lane >> 2;              // edge subgroup 0..15
    const float dg = dinv[g];
    const int beg = rowptr[g], end = rowptr[g + 1];
    const float4* h4 = (const float4*)hs;
    float4 acc = make_float4(0.f, 0.f, 0.f, 0.f);
    if (sub == 0) acc = h4[(long)g * 4 + q];  // self term
    for (int j0 = beg; j0 < end; j0 += 16) {
        int idx = j0 + sub;
        if (idx < end) {
            const int s = csr_src[idx];
            const float4 v = h4[(long)s * 4 + q];
            acc.x += v.x; acc.y += v.y; acc.z += v.z; acc.w += v.w;
        }
    }
#pragma unroll
    for (int m = 4; m <= 32; m <<= 1) {
        acc.x += __shfl_xor(acc.x, m, 64);
        acc.y += __shfl_xor(acc.y, m, 64);
        acc.z += __shfl_xor(acc.z, m, 64);
        acc.w += __shfl_xor(acc.w, m, 64);
    }
    if (sub == 0) {
        float4 v = make_float4(acc.x * dg, acc.y * dg, acc.z * dg, acc.w * dg);
        if (BIAS_RELU) {
            const float4 b = ((const float4*)bias)[q];
            v.x = fmaxf(v.x + b.x, 0.0f);
            v.y = fmaxf(v.y + b.y, 0.0f);
            v.z = fmaxf(v.z + b.z, 0.0f);
            v.w = fmaxf(v.w + b.w, 0.0f);
        }
        if (OUT_SCALE) { v.x *= dg; v.y *= dg; v.z *= dg; v.w *= dg; }
        ((float4*)outp)[(long)g * 4 + q] = v;
    }
}

// ---------------- fused gather16 + gemm2: C = dinv*relu(dg*(sum Bs)@W2 + b2) ----------------
__global__ __launch_bounds__(256) void g16gemm2_k(const int* __restrict__ rowptr,
                                                  const int* __restrict__ csr_src,
                                                  const float* __restrict__ dinv,
                                                  const float* __restrict__ hs,
                                                  const float* __restrict__ W2,
                                                  const float* __restrict__ b2,
                                                  float* __restrict__ outp, int n) {
    const int lane = threadIdx.x & 63;
    const int wid = blockIdx.x * 4 + (threadIdx.x >> 6);
    const int nWaves = gridDim.x * 4;
    float w2[16];
#pragma unroll
    for (int k = 0; k < 16; ++k) w2[k] = W2[k * 64 + lane];
    const float bm = b2[lane];
    const int q = lane & 3;
    const int sub = lane >> 2;
    const float4* h4 = (const float4*)hs;
    for (int g = wid; g < n; g += nWaves) {
        const float dg = dinv[g];
        const int beg = rowptr[g], end = rowptr[g + 1];
        float4 acc = make_float4(0.f, 0.f, 0.f, 0.f);
        if (sub == 0) acc = h4[(long)g * 4 + q];  // self term
        for (int j0 = beg; j0 < end; j0 += 16) {
            int idx = j0 + sub;
            if (idx < end) {
                const int s = csr_src[idx];
                const float4 v = h4[(long)s * 4 + q];
                acc.x += v.x; acc.y += v.y; acc.z += v.z; acc.w += v.w;
            }
        }
#pragma unroll
        for (int m = 4; m <= 32; m <<= 1) {
            acc.x += __shfl_xor(acc.x, m, 64);
            acc.y += __shfl_xor(acc.y, m, 64);
            acc.z += __shfl_xor(acc.z, m, 64);
            acc.w += __shfl_xor(acc.w, m, 64);
        }
        float t = 0.0f;
#pragma unroll
        for (int ql = 0; ql < 4; ++ql) {
            t = fmaf(rdl_f(acc.x, ql), w2[4 * ql + 0], t);
            t = fmaf(rdl_f(acc.y, ql), w2[4 * ql + 1], t);
            t = fmaf(rdl_f(acc.z, ql), w2[4 * ql + 2], t);
            t = fmaf(rdl_f(acc.w, ql), w2[4 * ql + 3], t);
        }
        float r = fmaxf(fmaf(dg, t, bm), 0.0f);   // dg*(sum)@W2 + b2, relu
        outp[(long)g * 64 + lane] = r * dg;        // pre-scaled for next gather
    }
}

// ---------------- pull-gather, 64 ch ----------------
__global__ __launch_bounds__(256) void gather64_k(const int* __restrict__ rowptr,
                                                  const int* __restrict__ csr_src,
                                                  const float* __restrict__ dinv,
                                                  const float* __restrict__ hs,
                                                  float* __restrict__ outp, int n) {
    const int g = (blockIdx.x * 256 + threadIdx.x) >> 6;
    if (g >= n) return;
    const int lane = threadIdx.x & 63;
    const int q = lane & 15;                // float4 index within 64-ch row
    const int sub = lane >> 4;              // edge subgroup 0..3
    const float dg = dinv[g];
    const int beg = rowptr[g], end = rowptr[g + 1];
    const float4* h4 = (const float4*)hs;
    float4 acc = make_float4(0.f, 0.f, 0.f, 0.f);
    if (sub == 0) acc = h4[(long)g * 16 + q];  // self term
    int j0 = beg;
    for (; j0 + 8 <= end; j0 += 8) {
        const int s0 = csr_src[j0 + sub];
        const int s1 = csr_src[j0 + 4 + sub];
        const float4 v0 = h4[(long)s0 * 16 + q];
        const float4 v1 = h4[(long)s1 * 16 + q];
        acc.x += v0.x + v1.x; acc.y += v0.y + v1.y;
        acc.z += v0.z + v1.z; acc.w += v0.w + v1.w;
    }
    for (; j0 < end; j0 += 4) {
        int idx = j0 + sub;
        if (idx < end) {
            const int s = csr_src[idx];
            const float4 v = h4[(long)s * 16 + q];
            acc.x += v.x; acc.y += v.y; acc.z += v.z; acc.w += v.w;
        }
    }
#pragma unroll
    for (int m = 16; m <= 32; m <<= 1) {
        acc.x += __shfl_xor(acc.x, m, 64);
        acc.y += __shfl_xor(acc.y, m, 64);
        acc.z += __shfl_xor(acc.z, m, 64);
        acc.w += __shfl_xor(acc.w, m, 64);
    }
    if (sub == 0) {
        ((float4*)outp)[(long)g * 16 + q] =
            make_float4(acc.x * dg, acc.y * dg, acc.z * dg, acc.w * dg);
    }
}

// ---------------- zero-LDS head, 8 nodes per wave ----------------
// N % 8 == 0. W3 cols in 128 VGPRs; readlane broadcasts; 16 FMA chains.
__global__ __launch_bounds__(256) void head_k(const float* __restrict__ aggS2,
                                              const float* __restrict__ W3,
                                              const float* __restrict__ b3,
                                              const float* __restrict__ Wfc,
                                              const float* __restrict__ bfc,
                                              float* __restrict__ out, int n) {
    const int lane = threadIdx.x & 63;
    const int wid = blockIdx.x * 4 + (threadIdx.x >> 6);
    const int nWaves = gridDim.x * 4;
    float w0[64], w1[64];
#pragma unroll
    for (int k = 0; k < 64; ++k) {
        w0[k] = W3[k * 128 + lane];
        w1[k] = W3[k * 128 + lane + 64];
    }
    const float bm0 = b3[lane], bm1 = b3[lane + 64];
    const float wf0 = Wfc[lane], wf1 = Wfc[lane + 64];
    const float bb = bfc[0];
    for (int g0 = wid * 8; g0 < n; g0 += nWaves * 8) {
        const float* base = aggS2 + (long)g0 * 64 + lane;
        float rv[8];
#pragma unroll
        for (int i = 0; i < 8; ++i) rv[i] = base[i * 64];
        float a0[8], a1[8];
#pragma unroll
        for (int i = 0; i < 8; ++i) { a0[i] = 0.f; a1[i] = 0.f; }
#pragma unroll
        for (int k = 0; k < 64; ++k) {
            const float wa = w0[k], wb = w1[k];
#pragma unroll
            for (int i = 0; i < 8; ++i) {
                const float xk = rdl_f(rv[i], k);
                a0[i] = fmaf(xk, wa, a0[i]);
                a1[i] = fmaf(xk, wb, a1[i]);
            }
        }
        float v[8];
#pragma unroll
        for (int i = 0; i < 8; ++i)
            v[i] = fmaxf(a0[i] + bm0, 0.f) * wf0 + fmaxf(a1[i] + bm1, 0.f) * wf1;
#pragma unroll
        for (int off = 32; off > 0; off >>= 1) {
#pragma unroll
            for (int i = 0; i < 8; ++i) v[i] += __shfl_down(v[i], off, 64);
        }
        if (lane == 0) {
            ((float4*)out)[(g0 >> 2) + 0] = make_float4(v[0] + bb, v[1] + bb, v[2] + bb, v[3] + bb);
            ((float4*)out)[(g0 >> 2) + 1] = make_float4(v[4] + bb, v[5] + bb, v[6] + bb, v[7] + bb);
        }
    }
}

extern "C" void kernel_launch(void* const* d_in, const int* in_sizes, int n_in,
                              void* d_out, int out_size, void* d_ws, size_t ws_size,
                              hipStream_t stream) {
    const float* x    = (const float*)d_in[0];
    const int*   ei   = (const int*)d_in[1];       // [2,E]: src = ei, dst = ei+E
    const float* W1   = (const float*)d_in[2];
    const float* b1   = (const float*)d_in[3];
    const float* W2   = (const float*)d_in[4];
    const float* b2   = (const float*)d_in[5];
    const float* W3   = (const float*)d_in[6];
    const float* b3   = (const float*)d_in[7];
    const float* Wfc  = (const float*)d_in[8];
    const float* bfc  = (const float*)d_in[9];
    float* out = (float*)d_out;

    const int* src = ei;
    const int* dst = ei + NE;

    // workspace layout (4-byte elems; arena offsets 16B-aligned):
    // dinv[N] | ideg[N] | rowptr[N+8] | bsum[512] | bofs[512] | rank[E]
    // | csr_src[E+64] | A[64N] | B[64N] | C[64N]
    float* dinv    = (float*)d_ws;
    int*   ideg    = (int*)(dinv + NN);
    int*   rowptr  = ideg + NN;
    int*   bsum    = rowptr + NN + 8;
    int*   bofs    = bsum + 512;
    int*   rank    = bofs + 512;
    int*   csr_src = rank + NE;
    float* A       = (float*)(csr_src + NE + 64);
    float* B       = A + (long)NN * 64;
    float* C       = B + (long)NN * 64;

    const int T = 256;

    // ---- [hist+rank ∥ gemm1'] ----
    hipMemsetAsync(ideg, 0, NN * sizeof(int), stream);
    const int histBlocks  = (NE + T - 1) / T;          // 6250
    const int gemm1Blocks = (NN + 15) / 16;            // 6250
    hist_gemm1_k<<<histBlocks + gemm1Blocks, T, 0, stream>>>(
        dst, ideg, rank, x, W1, A, NE, NN, histBlocks);

    // ---- scan (+dinv) ----
    scan_reduce_k<<<NB, T, 0, stream>>>(ideg, bsum, dinv, NN);
    scan_partials_k<<<1, 512, 0, stream>>>(bsum, bofs, NB);
    scan_final_k<<<NB, T, 0, stream>>>(ideg, bofs, rowptr, NN, NE);

    // ---- [fill ∥ A *= dinv] ----
    const int fillBlocks  = (NE + T - 1) / T;          // 6250
    const int scaleBlocks = (NN * 4 + T - 1) / T;      // 1563
    fill_scale_k<<<fillBlocks + scaleBlocks, T, 0, stream>>>(
        src, dst, rank, rowptr, csr_src, A, dinv, NE, NN, fillBlocks);

    // ---- B = dinv * relu(dg*(sum A) + b1)  (pre-scaled r1, 16ch) ----
    gather16_k<true, true><<<(NN + 3) / 4, T, 0, stream>>>(rowptr, csr_src, dinv, A, b1, B, NN);
    // ---- C = dinv * relu(dg*(sum B)@W2 + b2)  (pre-scaled r2, 64ch) ----
    g16gemm2_k<<<3072, T, 0, stream>>>(rowptr, csr_src, dinv, B, W2, b2, C, NN);
    // ---- A(64ch) = dg * sum C  (aggS2) ----
    gather64_k<<<(NN + 3) / 4, T, 0, stream>>>(rowptr, csr_src, dinv, C, A, NN);
    // ---- head: out = relu(A@W3 + b3).Wfc + bfc ----
    head_k<<<1024, T, 0, stream>>>(A, W3, b3, Wfc, bfc, out, NN);
}